// Round 3
// baseline (321.989 us; speedup 1.0000x reference)
//
#include <hip/hip_runtime.h>
#include <hip/hip_bf16.h>
#include <math.h>

typedef __attribute__((ext_vector_type(8))) short short8;
typedef __attribute__((ext_vector_type(4))) float f32x4;
typedef unsigned short ushort_t;

#define B_  4
#define T_  4096
#define C_  1024
#define HS_ 128
#define M_  (B_*T_)   // 16384

// scale folded into q: C^-0.5 * log2(e)  -> scores come out of MFMA in log2 units
#define QSCALE 0.04508422002778011f

__device__ __forceinline__ ushort_t f2bf(float f) {      // RNE
    unsigned int u = __float_as_uint(f);
    u = (u + 0x7FFFu + ((u >> 16) & 1u)) >> 16;
    return (ushort_t)u;
}
__device__ __forceinline__ ushort_t f2bf_fast(float f) { // round-half-up (p in [0,1])
    return (ushort_t)((__float_as_uint(f) + 0x8000u) >> 16);
}

// ---------------------------------------------------------------------------
// Kernel 1: convert x fp32->bf16 (blocks 0..8191) and W->WT bf16 transposed
// (blocks 8192..9727).  WT layout: [m][h][k]  (B-fragment layout for GEMM)
// ---------------------------------------------------------------------------
__global__ __launch_bounds__(256) void convert_kernel(
    const float* __restrict__ x, const float* __restrict__ Wq,
    const float* __restrict__ Wk, const float* __restrict__ Wv,
    ushort_t* __restrict__ xb, ushort_t* __restrict__ WT3)
{
    int blk = blockIdx.x, tid = threadIdx.x;
    if (blk < 8192) {
        size_t e = ((size_t)blk * 256 + tid) * 8;
        float4 a = *(const float4*)(x + e);
        float4 b = *(const float4*)(x + e + 4);
        short8 sv;
        sv[0]=f2bf(a.x); sv[1]=f2bf(a.y); sv[2]=f2bf(a.z); sv[3]=f2bf(a.w);
        sv[4]=f2bf(b.x); sv[5]=f2bf(b.y); sv[6]=f2bf(b.z); sv[7]=f2bf(b.w);
        *(short8*)(xb + e) = sv;
    } else {
        int id = (blk - 8192) * 256 + tid;      // 0 .. 393215
        int h  = id & 127;
        int kk = (id >> 7) & 1023;
        int m  = id >> 17;
        const float* W = (m == 0) ? Wq : (m == 1) ? Wk : Wv;
        WT3[(size_t)(m * 128 + h) * 1024 + kk] = f2bf(W[(size_t)kk * 128 + h]);
    }
}

// ---------------------------------------------------------------------------
// Kernel 2: qkv = x @ W, bf16 MFMA.  Block: 64 rows x 128 cols, 4 waves.
// grid = (256 m-tiles, 3 matrices).  mm==0 -> q (pre-scaled), mm==1 -> k,
// mm==2 -> vT written transposed [b][h][t].
// ---------------------------------------------------------------------------
__global__ __launch_bounds__(256, 3) void qkv_gemm(
    const ushort_t* __restrict__ xb, const ushort_t* __restrict__ WT3,
    ushort_t* __restrict__ q, ushort_t* __restrict__ k,
    ushort_t* __restrict__ vT)
{
    __shared__ ushort_t sA[64 * 72];    // [m][k] bf16
    __shared__ ushort_t sB[128 * 72];   // [n][k] bf16
    const int tid  = threadIdx.x;
    const int mt   = blockIdx.x;
    const int mm   = blockIdx.y;
    const int t0   = mt * 64;
    const int wid  = tid >> 6, lane = tid & 63;
    const int quad = lane >> 4, l15 = lane & 15;

    f32x4 acc[8];
#pragma unroll
    for (int nt = 0; nt < 8; ++nt) acc[nt] = (f32x4)0.f;

    const ushort_t* WTm = WT3 + (size_t)mm * 128 * 1024;

    for (int kc = 0; kc < C_; kc += 64) {
        __syncthreads();
#pragma unroll
        for (int j = 0; j < 2; ++j) {
            int c = tid + 256 * j;            // 512 chunks of 8
            int row = c >> 3, c8 = c & 7;
            *(short8*)&sA[row * 72 + c8 * 8] =
                *(const short8*)(xb + (size_t)(t0 + row) * C_ + kc + c8 * 8);
        }
#pragma unroll
        for (int j = 0; j < 4; ++j) {
            int c = tid + 256 * j;            // 1024 chunks of 8
            int row = c >> 3, c8 = c & 7;
            *(short8*)&sB[row * 72 + c8 * 8] =
                *(const short8*)(WTm + (size_t)row * 1024 + kc + c8 * 8);
        }
        __syncthreads();
        short8 af0 = *(short8*)&sA[(wid * 16 + l15) * 72 + quad * 8];
        short8 af1 = *(short8*)&sA[(wid * 16 + l15) * 72 + 32 + quad * 8];
#pragma unroll
        for (int nt = 0; nt < 8; ++nt) {
            short8 bf0 = *(short8*)&sB[(nt * 16 + l15) * 72 + quad * 8];
            short8 bf1 = *(short8*)&sB[(nt * 16 + l15) * 72 + 32 + quad * 8];
            acc[nt] = __builtin_amdgcn_mfma_f32_16x16x32_bf16(af0, bf0, acc[nt], 0, 0, 0);
            acc[nt] = __builtin_amdgcn_mfma_f32_16x16x32_bf16(af1, bf1, acc[nt], 0, 0, 0);
        }
    }
    if (mm == 0) {
#pragma unroll
        for (int nt = 0; nt < 8; ++nt)
#pragma unroll
            for (int rr = 0; rr < 4; ++rr) {
                int t = t0 + wid * 16 + quad * 4 + rr;
                int h = nt * 16 + l15;
                q[(size_t)t * HS_ + h] = f2bf(acc[nt][rr] * QSCALE);
            }
    } else if (mm == 1) {
#pragma unroll
        for (int nt = 0; nt < 8; ++nt)
#pragma unroll
            for (int rr = 0; rr < 4; ++rr) {
                int t = t0 + wid * 16 + quad * 4 + rr;
                int h = nt * 16 + l15;
                k[(size_t)t * HS_ + h] = f2bf(acc[nt][rr]);
            }
    } else {
        const int b = t0 >> 12;
#pragma unroll
        for (int nt = 0; nt < 8; ++nt)
#pragma unroll
            for (int rr = 0; rr < 4; ++rr) {
                int t = t0 + wid * 16 + quad * 4 + rr;
                int h = nt * 16 + l15;
                vT[((size_t)(b * HS_) + h) * T_ + (t & (T_ - 1))] = f2bf(acc[nt][rr]);
            }
    }
}

// ---------------------------------------------------------------------------
// Kernel 3: causal flash attention, split-K, wave-local softmax, no barriers.
// grid = B*256 tiles of 16 q-rows; 4 waves/block = 4 key segments of the
// tile's causal range.  K/V fragments read directly from L2 (no LDS staging).
// Partials (O, m, l) per (segment, tile) -> combine kernel.
// ---------------------------------------------------------------------------
#define SPP 136   // sP row stride (bf16)

__global__ __launch_bounds__(256) void attn_split(
    const ushort_t* __restrict__ q, const ushort_t* __restrict__ k,
    const ushort_t* __restrict__ vT, float* __restrict__ Opart,
    float* __restrict__ mseg, float* __restrict__ lseg)
{
    __shared__ ushort_t sP[4][16 * SPP];     // per-wave P scratch (17.4 KB)

    const int tid  = threadIdx.x;
    const int gt   = blockIdx.x;             // global tile id 0..1023
    const int b    = gt >> 8, qt = gt & 255;
    const int qb   = qt << 4;
    const int w    = tid >> 6, lane = tid & 63;
    const int quad = lane >> 4, l15 = lane & 15;

    const int nkc = (qt + 8) >> 3;                    // 128-key chunks in range
    const int k0  = (nkc * w) >> 2;
    const int k1  = (nkc * (w + 1)) >> 2;

    const size_t bT = (size_t)b << 12;

    short8 qf[4];
#pragma unroll
    for (int kf = 0; kf < 4; ++kf)
        qf[kf] = *(const short8*)(q + (bT + qb + l15) * HS_ + kf * 32 + quad * 8);

    f32x4 O[8];
#pragma unroll
    for (int nt = 0; nt < 8; ++nt) O[nt] = (f32x4)0.f;
    float mst[4], lst[4];
#pragma unroll
    for (int rr = 0; rr < 4; ++rr) { mst[rr] = -1e30f; lst[rr] = 0.f; }

    for (int kc = k0; kc < k1; ++kc) {
        const int kb = kc << 7;
        // ---- QK^T: scores already in log2 units (scale folded into q) ----
        f32x4 S[8];
#pragma unroll
        for (int nt = 0; nt < 8; ++nt) S[nt] = (f32x4)0.f;
#pragma unroll
        for (int nt = 0; nt < 8; ++nt) {
            const ushort_t* kp = k + (bT + kb + nt * 16 + l15) * HS_ + quad * 8;
#pragma unroll
            for (int kf = 0; kf < 4; ++kf)
                S[nt] = __builtin_amdgcn_mfma_f32_16x16x32_bf16(
                    qf[kf], *(const short8*)(kp + kf * 32), S[nt], 0, 0, 0);
        }
        // ---- mask (only the diagonal chunk; provably the last one) ----
        if (kc == nkc - 1) {
#pragma unroll
            for (int nt = 0; nt < 8; ++nt)
#pragma unroll
                for (int rr = 0; rr < 4; ++rr)
                    if (kb + nt * 16 + l15 > qb + quad * 4 + rr)
                        S[nt][rr] = -1e30f;
        }
        // ---- wave-local online softmax (rows owned by this wave) ----
        float mN[4], al[4], ps[4];
#pragma unroll
        for (int rr = 0; rr < 4; ++rr) {
            float m = S[0][rr];
#pragma unroll
            for (int nt = 1; nt < 8; ++nt) m = fmaxf(m, S[nt][rr]);
#pragma unroll
            for (int msk = 1; msk < 16; msk <<= 1)
                m = fmaxf(m, __shfl_xor(m, msk));
            m = fmaxf(m, mst[rr]);
            al[rr] = exp2f(mst[rr] - m);
            mN[rr] = m; mst[rr] = m;
            ps[rr] = 0.f;
        }
#pragma unroll
        for (int nt = 0; nt < 8; ++nt)
#pragma unroll
            for (int rr = 0; rr < 4; ++rr) {
                float p = exp2f(S[nt][rr] - mN[rr]);
                ps[rr] += p;
                sP[w][(quad * 4 + rr) * SPP + nt * 16 + l15] = f2bf_fast(p);
            }
#pragma unroll
        for (int rr = 0; rr < 4; ++rr)
            lst[rr] = lst[rr] * al[rr] + ps[rr];
#pragma unroll
        for (int nt = 0; nt < 8; ++nt)
#pragma unroll
            for (int rr = 0; rr < 4; ++rr)
                O[nt][rr] *= al[rr];
        // ---- PV: P via LDS round-trip (C-layout -> A-layout), V^T from L2 ----
        short8 pf[4];
#pragma unroll
        for (int kf = 0; kf < 4; ++kf)
            pf[kf] = *(short8*)&sP[w][l15 * SPP + kf * 32 + quad * 8];
#pragma unroll
        for (int nt = 0; nt < 8; ++nt) {
            const ushort_t* vp = vT + ((size_t)(b * HS_) + nt * 16 + l15) * T_ + kb + quad * 8;
#pragma unroll
            for (int kf = 0; kf < 4; ++kf)
                O[nt] = __builtin_amdgcn_mfma_f32_16x16x32_bf16(
                    pf[kf], *(const short8*)(vp + kf * 32), O[nt], 0, 0, 0);
        }
    }
    // ---- reduce l across the 16 key-lanes, store partials ----
#pragma unroll
    for (int rr = 0; rr < 4; ++rr)
#pragma unroll
        for (int msk = 1; msk < 16; msk <<= 1)
            lst[rr] += __shfl_xor(lst[rr], msk);

    const int base = (w * 1024 + gt) * 16;
#pragma unroll
    for (int nt = 0; nt < 8; ++nt)
#pragma unroll
        for (int rr = 0; rr < 4; ++rr)
            Opart[(size_t)(base + quad * 4 + rr) * 128 + nt * 16 + l15] = O[nt][rr];
    if (l15 == 0)
#pragma unroll
        for (int rr = 0; rr < 4; ++rr) {
            mseg[base + quad * 4 + rr] = mst[rr];
            lseg[base + quad * 4 + rr] = lst[rr];
        }
}

// ---------------------------------------------------------------------------
// Kernel 4: combine split-K partials.  grid = 1024 tiles, 256 thr.
// ---------------------------------------------------------------------------
__global__ __launch_bounds__(256) void combine_kernel(
    const float* __restrict__ Opart, const float* __restrict__ mseg,
    const float* __restrict__ lseg, float* __restrict__ out)
{
    const int tid = threadIdx.x;
    const int gt  = blockIdx.x;
    const int b   = gt >> 8, qt = gt & 255;
    const int c   = tid & 127;
    const int rh  = tid >> 7;
#pragma unroll
    for (int i = 0; i < 8; ++i) {
        int r = rh * 8 + i;
        int sbase = gt * 16 + r;
        float m0 = mseg[sbase], m1 = mseg[16384 + sbase];
        float m2 = mseg[32768 + sbase], m3 = mseg[49152 + sbase];
        float ms = fmaxf(fmaxf(m0, m1), fmaxf(m2, m3));
        float w0 = exp2f(m0 - ms), w1 = exp2f(m1 - ms);
        float w2 = exp2f(m2 - ms), w3 = exp2f(m3 - ms);
        float denom = w0 * lseg[sbase] + w1 * lseg[16384 + sbase]
                    + w2 * lseg[32768 + sbase] + w3 * lseg[49152 + sbase];
        size_t ob = (size_t)(gt * 16 + r) * 128 + c;
        float num = w0 * Opart[ob] + w1 * Opart[2097152 + ob]
                  + w2 * Opart[4194304 + ob] + w3 * Opart[6291456 + ob];
        out[((size_t)(b * T_) + qt * 16 + r) * HS_ + c] = num / denom;
    }
}

// ---------------------------------------------------------------------------
extern "C" void kernel_launch(void* const* d_in, const int* in_sizes, int n_in,
                              void* d_out, int out_size, void* d_ws, size_t ws_size,
                              hipStream_t stream)
{
    const float* x  = (const float*)d_in[0];
    const float* Wq = (const float*)d_in[1];
    const float* Wk = (const float*)d_in[2];
    const float* Wv = (const float*)d_in[3];
    float* out = (float*)d_out;

    // workspace layout (ushort units unless noted)
    ushort_t* xb  = (ushort_t*)d_ws;               // 16,777,216 (33.5 MB)
    ushort_t* WT3 = xb + 16777216;                 // 393,216
    ushort_t* q   = WT3 + 393216;                  // 2,097,152
    ushort_t* k   = q + 2097152;                   // 2,097,152
    ushort_t* vT  = k + 2097152;                   // 2,097,152
    float* Opart  = (float*)xb;                    // ALIAS xb (dead after gemm): 8,388,608 floats
    float* mseg   = (float*)(vT + 2097152);        // 65,536 floats
    float* lseg   = mseg + 65536;                  // 65,536 floats

    convert_kernel<<<9728, 256, 0, stream>>>(x, Wq, Wk, Wv, xb, WT3);
    qkv_gemm<<<dim3(256, 3), 256, 0, stream>>>(xb, WT3, q, k, vT);
    attn_split<<<1024, 256, 0, stream>>>(q, k, vT, Opart, mseg, lseg);
    combine_kernel<<<1024, 256, 0, stream>>>(Opart, mseg, lseg, out);
}

// Round 4
// 218.136 us; speedup vs baseline: 1.4761x; 1.4761x over previous
//
#include <hip/hip_runtime.h>
#include <hip/hip_bf16.h>
#include <math.h>

typedef __attribute__((ext_vector_type(8))) short short8;
typedef __attribute__((ext_vector_type(4))) float f32x4;
typedef unsigned short ushort_t;

#define B_  4
#define T_  4096
#define C_  1024
#define HS_ 128

// scale folded into q at GEMM epilogue: C^-0.5 * log2(e) -> scores in log2 units
#define QSCALE 0.04508422002778011f

__device__ __forceinline__ ushort_t f2bf(float f) {      // RNE
    unsigned int u = __float_as_uint(f);
    u = (u + 0x7FFFu + ((u >> 16) & 1u)) >> 16;
    return (ushort_t)u;
}
__device__ __forceinline__ ushort_t f2bf_fast(float f) { // round-half-up (p in [0,1])
    return (ushort_t)((__float_as_uint(f) + 0x8000u) >> 16);
}

// async global->LDS, 16B per lane; LDS dest must be wave-uniform base + lane*16
__device__ __forceinline__ void async16(const void* g, void* l) {
    __builtin_amdgcn_global_load_lds(
        (const __attribute__((address_space(1))) unsigned int*)g,
        (__attribute__((address_space(3))) unsigned int*)l, 16, 0, 0);
}

// ---------------------------------------------------------------------------
// Kernel 1: x fp32->bf16 (blocks 0..8191); W -> WT bf16 [m][h][k] (rest)
// ---------------------------------------------------------------------------
__global__ __launch_bounds__(256) void convert_kernel(
    const float* __restrict__ x, const float* __restrict__ Wq,
    const float* __restrict__ Wk, const float* __restrict__ Wv,
    ushort_t* __restrict__ xb, ushort_t* __restrict__ WT3)
{
    int blk = blockIdx.x, tid = threadIdx.x;
    if (blk < 8192) {
        size_t e = ((size_t)blk * 256 + tid) * 8;
        float4 a = *(const float4*)(x + e);
        float4 b = *(const float4*)(x + e + 4);
        short8 sv;
        sv[0]=f2bf(a.x); sv[1]=f2bf(a.y); sv[2]=f2bf(a.z); sv[3]=f2bf(a.w);
        sv[4]=f2bf(b.x); sv[5]=f2bf(b.y); sv[6]=f2bf(b.z); sv[7]=f2bf(b.w);
        *(short8*)(xb + e) = sv;
    } else {
        int id = (blk - 8192) * 256 + tid;      // 0 .. 393215
        int h  = id & 127;
        int kk = (id >> 7) & 1023;
        int m  = id >> 17;
        const float* W = (m == 0) ? Wq : (m == 1) ? Wk : Wv;
        WT3[(size_t)(m * 128 + h) * 1024 + kk] = f2bf(W[(size_t)kk * 128 + h]);
    }
}

// ---------------------------------------------------------------------------
// Kernel 2: qkv = x @ W.  128x128 tile, BK=64, 4 waves 2x2 (64x64 each),
// global_load_lds staging with XOR swizzle.  grid = (128 m-tiles, 3).
// mm==0 -> q (pre-scaled); mm==1 -> k; mm==2 -> vT [b][h][t] via LDS transpose.
// ---------------------------------------------------------------------------
__global__ __launch_bounds__(256, 3) void qkv_gemm(
    const ushort_t* __restrict__ xb, const ushort_t* __restrict__ WT3,
    ushort_t* __restrict__ q, ushort_t* __restrict__ k,
    ushort_t* __restrict__ vT)
{
    __shared__ ushort_t smem[128 * 132];      // 33.8 KB (epilogue transpose reuses)
    ushort_t* sA = smem;                      // [128][64] swizzled
    ushort_t* sB = smem + 8192;               // [128][64] swizzled

    const int tid  = threadIdx.x;
    const int mt0  = blockIdx.x;
    const int mm   = blockIdx.y;
    const int t0   = mt0 * 128;
    const int w    = tid >> 6, lane = tid & 63;
    const int quad = lane >> 4, l15 = lane & 15;
    const int wr   = w >> 1, wc = w & 1;

    const ushort_t* WTm = WT3 + (size_t)mm * (128 * 1024);

    f32x4 acc[4][4];
#pragma unroll
    for (int mt = 0; mt < 4; ++mt)
#pragma unroll
        for (int nt = 0; nt < 4; ++nt) acc[mt][nt] = (f32x4)0.f;

    for (int kc = 0; kc < C_; kc += 64) {
        __syncthreads();
#pragma unroll
        for (int j = 0; j < 4; ++j) {
            int d = j * 256 + tid;            // 16B-chunk index, 1024 per tile
            int row = d >> 3, c = d & 7;
            async16(xb + (size_t)(t0 + row) * C_ + kc + ((c ^ (row & 7)) * 8),
                    sA + d * 8);
        }
#pragma unroll
        for (int j = 0; j < 4; ++j) {
            int d = j * 256 + tid;
            int row = d >> 3, c = d & 7;
            async16(WTm + (size_t)row * C_ + kc + ((c ^ (row & 7)) * 8),
                    sB + d * 8);
        }
        __syncthreads();
#pragma unroll
        for (int kf = 0; kf < 2; ++kf) {
            short8 af[4], bf[4];
#pragma unroll
            for (int mt = 0; mt < 4; ++mt) {
                int row = wr * 64 + mt * 16 + l15;
                af[mt] = *(const short8*)&sA[row * 64 + (((kf * 4 + quad) ^ (row & 7)) * 8)];
            }
#pragma unroll
            for (int nt = 0; nt < 4; ++nt) {
                int row = wc * 64 + nt * 16 + l15;
                bf[nt] = *(const short8*)&sB[row * 64 + (((kf * 4 + quad) ^ (row & 7)) * 8)];
            }
#pragma unroll
            for (int mt = 0; mt < 4; ++mt)
#pragma unroll
                for (int nt = 0; nt < 4; ++nt)
                    acc[mt][nt] = __builtin_amdgcn_mfma_f32_16x16x32_bf16(
                        af[mt], bf[nt], acc[mt][nt], 0, 0, 0);
        }
    }

    if (mm < 2) {
        ushort_t* outp = (mm == 0) ? q : k;
        const float s = (mm == 0) ? QSCALE : 1.0f;
#pragma unroll
        for (int mt = 0; mt < 4; ++mt)
#pragma unroll
            for (int nt = 0; nt < 4; ++nt)
#pragma unroll
                for (int rr = 0; rr < 4; ++rr) {
                    int t = t0 + wr * 64 + mt * 16 + quad * 4 + rr;
                    int h = wc * 64 + nt * 16 + l15;
                    outp[(size_t)t * HS_ + h] = f2bf(acc[mt][nt][rr] * s);
                }
    } else {
        // transpose through LDS: sT[t_local][h], stride 132
        __syncthreads();
        ushort_t* sT = smem;
#pragma unroll
        for (int mt = 0; mt < 4; ++mt)
#pragma unroll
            for (int nt = 0; nt < 4; ++nt)
#pragma unroll
                for (int rr = 0; rr < 4; ++rr)
                    sT[(wr * 64 + mt * 16 + quad * 4 + rr) * 132
                       + wc * 64 + nt * 16 + l15] = f2bf(acc[mt][nt][rr]);
        __syncthreads();
        const int b  = t0 >> 12;
        const int tl = t0 & (T_ - 1);
        const int hr = tid >> 1, th = tid & 1;
#pragma unroll
        for (int g = 0; g < 8; ++g) {
            short8 o;
#pragma unroll
            for (int i = 0; i < 8; ++i)
                o[i] = (short)sT[(th * 64 + g * 8 + i) * 132 + hr];
            *(short8*)(vT + ((size_t)(b * HS_) + hr) * T_ + tl + th * 64 + g * 8) = o;
        }
    }
}

// ---------------------------------------------------------------------------
// Kernel 3: causal flash attention.  Q-tile = 128 rows (4 waves x 32 rows,
// wave-local softmax), 64-key chunks staged in LDS (swizzled, async DMA).
// Tiles split into 1024-key segments -> 320 uniform-ish blocks; partials
// (O, m, l) per segment -> combine kernel.
// ---------------------------------------------------------------------------
#define SPW 72   // sP row stride (shorts)

__global__ __launch_bounds__(256, 2) void attn_seg(
    const ushort_t* __restrict__ q, const ushort_t* __restrict__ k,
    const ushort_t* __restrict__ vT, float* __restrict__ Opart,
    float* __restrict__ mseg, float* __restrict__ lseg)
{
    __shared__ ushort_t sK[64 * 128];        // [key][h]   swizzled (^row&15)
    __shared__ ushort_t sV[128 * 64];        // [h][key]   swizzled (^row&7)
    __shared__ ushort_t sP[4][32 * SPW];     // per-wave P (wave-private)

    const int tid  = threadIdx.x;
    const int blk  = blockIdx.x;             // 0..319
    const int b    = blk / 80;
    const int r    = blk - b * 80;
    int i, s;
    if (r < 8)       { i = r;                    s = 0; }
    else if (r < 24) { int t = r - 8;  i = 8  + (t >> 1); s = t & 1; }
    else if (r < 48) { int t = r - 24; i = 16 + t / 3;    s = t - (i - 16) * 3 - 24 + 0; s = (r - 24) % 3; }
    else             { int t = r - 48; i = 24 + (t >> 2); s = t & 3; }

    const int qb   = i << 7;                 // tile's first q-row (within batch)
    const int tile = b * 32 + i;             // global tile id 0..127
    const int nkc  = (i + 1) * 2;            // 64-key chunks in causal range
    const int c0   = s * 16;
    const int c1   = (c0 + 16 < nkc) ? c0 + 16 : nkc;

    const int w    = tid >> 6, lane = tid & 63;
    const int quad = lane >> 4, l15 = lane & 15;
    const size_t bT = (size_t)b << 12;

    // Q fragments (A-layout straight from global), wave's 32 rows
    short8 qf[2][4];
#pragma unroll
    for (int mt = 0; mt < 2; ++mt)
#pragma unroll
        for (int kf = 0; kf < 4; ++kf)
            qf[mt][kf] = *(const short8*)(
                q + (bT + qb + w * 32 + mt * 16 + l15) * HS_ + kf * 32 + quad * 8);

    f32x4 O[2][8];
#pragma unroll
    for (int mt = 0; mt < 2; ++mt)
#pragma unroll
        for (int nt = 0; nt < 8; ++nt) O[mt][nt] = (f32x4)0.f;
    float mst[2][4], lst[2][4];
#pragma unroll
    for (int mt = 0; mt < 2; ++mt)
#pragma unroll
        for (int rr = 0; rr < 4; ++rr) { mst[mt][rr] = -1e30f; lst[mt][rr] = 0.f; }

    for (int c = c0; c < c1; ++c) {
        const int kb = c << 6;
        __syncthreads();                     // prior-iter LDS reads done
        // stage K chunk: [64 keys][128 h], rows 256B = 16 chunks, swizzle ^(row&15)
#pragma unroll
        for (int j = 0; j < 4; ++j) {
            int d = j * 256 + tid;
            int row = d >> 4, cs = d & 15;
            async16(k + (bT + kb + row) * HS_ + ((cs ^ (row & 15)) * 8), sK + d * 8);
        }
        // stage V^T chunk: [128 h][64 keys], rows 128B = 8 chunks, swizzle ^(row&7)
#pragma unroll
        for (int j = 0; j < 4; ++j) {
            int d = j * 256 + tid;
            int row = d >> 3, cs = d & 7;
            async16(vT + ((size_t)(b * HS_) + row) * T_ + kb + ((cs ^ (row & 7)) * 8),
                    sV + d * 8);
        }
        __syncthreads();                     // DMA drained for all waves

        // ---- QK^T: S[mt][nt], keys nt*16+l15 ----
        f32x4 S[2][4];
#pragma unroll
        for (int mt = 0; mt < 2; ++mt)
#pragma unroll
            for (int nt = 0; nt < 4; ++nt) S[mt][nt] = (f32x4)0.f;
#pragma unroll
        for (int nt = 0; nt < 4; ++nt)
#pragma unroll
            for (int kf = 0; kf < 4; ++kf) {
                int row = nt * 16 + l15;
                short8 bf = *(const short8*)&sK[row * 128 + (((kf * 4 + quad) ^ (row & 15)) * 8)];
#pragma unroll
                for (int mt = 0; mt < 2; ++mt)
                    S[mt][nt] = __builtin_amdgcn_mfma_f32_16x16x32_bf16(
                        qf[mt][kf], bf, S[mt][nt], 0, 0, 0);
            }
        // ---- causal mask: only the last two chunks of the tile touch diagonal
        if (c >= nkc - 2) {
#pragma unroll
            for (int mt = 0; mt < 2; ++mt)
#pragma unroll
                for (int nt = 0; nt < 4; ++nt)
#pragma unroll
                    for (int rr = 0; rr < 4; ++rr)
                        if (kb + nt * 16 + l15 > qb + w * 32 + mt * 16 + quad * 4 + rr)
                            S[mt][nt][rr] = -1e30f;
        }
        // ---- wave-local online softmax ----
        float ps[2][4];
#pragma unroll
        for (int mt = 0; mt < 2; ++mt)
#pragma unroll
            for (int rr = 0; rr < 4; ++rr) {
                float m = fmaxf(fmaxf(S[mt][0][rr], S[mt][1][rr]),
                                fmaxf(S[mt][2][rr], S[mt][3][rr]));
#pragma unroll
                for (int msk = 1; msk < 16; msk <<= 1)
                    m = fmaxf(m, __shfl_xor(m, msk));
                m = fmaxf(m, mst[mt][rr]);
                float al = exp2f(mst[mt][rr] - m);
                mst[mt][rr] = m;
                lst[mt][rr] *= al;
                ps[mt][rr] = 0.f;
#pragma unroll
                for (int nt = 0; nt < 8; ++nt) O[mt][nt][rr] *= al;
            }
#pragma unroll
        for (int mt = 0; mt < 2; ++mt)
#pragma unroll
            for (int nt = 0; nt < 4; ++nt)
#pragma unroll
                for (int rr = 0; rr < 4; ++rr) {
                    float p = exp2f(S[mt][nt][rr] - mst[mt][rr]);
                    ps[mt][rr] += p;
                    sP[w][(mt * 16 + quad * 4 + rr) * SPW + nt * 16 + l15] = f2bf_fast(p);
                }
#pragma unroll
        for (int mt = 0; mt < 2; ++mt)
#pragma unroll
            for (int rr = 0; rr < 4; ++rr) lst[mt][rr] += ps[mt][rr];

        // ---- PV: P (LDS round-trip, wave-private) x V^T fragments ----
#pragma unroll
        for (int mt = 0; mt < 2; ++mt)
#pragma unroll
            for (int kf = 0; kf < 2; ++kf) {
                short8 pf = *(short8*)&sP[w][(mt * 16 + l15) * SPW + kf * 32 + quad * 8];
#pragma unroll
                for (int nt = 0; nt < 8; ++nt) {
                    int row = nt * 16 + l15;
                    short8 vf = *(const short8*)&sV[row * 64 + (((kf * 4 + quad) ^ (row & 7)) * 8)];
                    O[mt][nt] = __builtin_amdgcn_mfma_f32_16x16x32_bf16(
                        pf, vf, O[mt][nt], 0, 0, 0);
                }
            }
    }

    // ---- finalize l (sum over the 16 key-lanes), store partials ----
#pragma unroll
    for (int mt = 0; mt < 2; ++mt)
#pragma unroll
        for (int rr = 0; rr < 4; ++rr)
#pragma unroll
            for (int msk = 1; msk < 16; msk <<= 1)
                lst[mt][rr] += __shfl_xor(lst[mt][rr], msk);

    const size_t segtile = (size_t)(s * 128 + tile);
#pragma unroll
    for (int mt = 0; mt < 2; ++mt) {
        const int row = w * 32 + mt * 16 + quad * 4;
#pragma unroll
        for (int nt = 0; nt < 8; ++nt)
#pragma unroll
            for (int rr = 0; rr < 4; ++rr)
                Opart[(segtile * 128 + row + rr) * 128 + nt * 16 + l15] = O[mt][nt][rr];
        if (l15 == 0)
#pragma unroll
            for (int rr = 0; rr < 4; ++rr) {
                mseg[segtile * 128 + row + rr] = mst[mt][rr];
                lseg[segtile * 128 + row + rr] = lst[mt][rr];
            }
    }
}

// ---------------------------------------------------------------------------
// Kernel 4: combine per-segment partials.  grid = 128 tiles, 256 thr.
// ---------------------------------------------------------------------------
__global__ __launch_bounds__(256) void combine_kernel(
    const float* __restrict__ Opart, const float* __restrict__ mseg,
    const float* __restrict__ lseg, float* __restrict__ out)
{
    const int tile = blockIdx.x;
    const int b = tile >> 5, i = tile & 31;
    const int nseg = (i + 8) >> 3;
    const int tid = threadIdx.x;
    const int row = tid >> 1;
    const int ch  = (tid & 1) * 64;

    float wgt[4];
    float M = -1e30f;
    for (int s = 0; s < nseg; ++s)
        M = fmaxf(M, mseg[(size_t)(s * 128 + tile) * 128 + row]);
    float den = 0.f;
    for (int s = 0; s < nseg; ++s) {
        float ww = exp2f(mseg[(size_t)(s * 128 + tile) * 128 + row] - M);
        wgt[s] = ww;
        den += ww * lseg[(size_t)(s * 128 + tile) * 128 + row];
    }
    const float inv = 1.0f / den;

    for (int g = 0; g < 16; ++g) {
        int cc = ch + g * 4;
        f32x4 a = (f32x4)0.f;
        for (int s = 0; s < nseg; ++s) {
            f32x4 o = *(const f32x4*)&Opart[((size_t)(s * 128 + tile) * 128 + row) * 128 + cc];
            a += o * wgt[s];
        }
        a *= inv;
        *(f32x4*)&out[((size_t)(b * T_) + i * 128 + row) * HS_ + cc] = a;
    }
}

// ---------------------------------------------------------------------------
extern "C" void kernel_launch(void* const* d_in, const int* in_sizes, int n_in,
                              void* d_out, int out_size, void* d_ws, size_t ws_size,
                              hipStream_t stream)
{
    const float* x  = (const float*)d_in[0];
    const float* Wq = (const float*)d_in[1];
    const float* Wk = (const float*)d_in[2];
    const float* Wv = (const float*)d_in[3];
    float* out = (float*)d_out;

    ushort_t* xb  = (ushort_t*)d_ws;               // 16,777,216 shorts (33.5 MB)
    ushort_t* WT3 = xb + 16777216;                 // 393,216
    ushort_t* q   = WT3 + 393216;                  // 2,097,152
    ushort_t* k   = q + 2097152;                   // 2,097,152
    ushort_t* vT  = k + 2097152;                   // 2,097,152  [B][HS][T]
    float* mseg   = (float*)(vT + 2097152);        // 65,536
    float* lseg   = mseg + 65536;                  // 65,536
    float* Opart  = (float*)xb;                    // alias xb (dead after gemm): 4 x 8,388,608 floats

    convert_kernel<<<9728, 256, 0, stream>>>(x, Wq, Wk, Wv, xb, WT3);
    qkv_gemm<<<dim3(128, 3), 256, 0, stream>>>(xb, WT3, q, k, vT);
    attn_seg<<<320, 256, 0, stream>>>(q, k, vT, Opart, mseg, lseg);
    combine_kernel<<<128, 256, 0, stream>>>(Opart, mseg, lseg, out);
}